// Round 4
// baseline (114.138 us; speedup 1.0000x reference)
//
#include <hip/hip_runtime.h>

#define T_LEN 512
#define LOG2E 1.4426950408889634f

// readlane: broadcast from a lane into a wave-uniform (SGPR) value
__device__ __forceinline__ float rl(float v, int lane) {
    return __int_as_float(__builtin_amdgcn_readlane(__float_as_int(v), lane));
}

// quad_perm DPP (C-side epilogue use)
template<int CTRL>
__device__ __forceinline__ float qperm(float v) {
    return __int_as_float(__builtin_amdgcn_mov_dpp(__float_as_int(v), CTRL, 0xF, 0xF, true));
}

// Layout: one 64-lane wave per batch element.
// lane l -> gate g = l&3 (0:i 1:f 2:g 3:o), hidden k = l>>2; weight row = g*16+k.
// Hand-written asm inner loop. Hazard protection (the R2 NaN): TRANS results
// (v_exp/v_rcp) need wait states before a VALU read; also VALU->DPP-src and
// VALU->readlane-src hazards, and a trailing nop so compiler-side reads of the
// readlane-written SGPRs are safe across the asm boundary.
__global__ __launch_bounds__(256, 2) void bilstm_head_kernel(
    const float* __restrict__ x,
    const float* __restrict__ W_ih_f, const float* __restrict__ W_hh_f,
    const float* __restrict__ b_ih_f, const float* __restrict__ b_hh_f,
    const float* __restrict__ W_ih_r, const float* __restrict__ W_hh_r,
    const float* __restrict__ b_ih_r, const float* __restrict__ b_hh_r,
    const float* __restrict__ W1, const float* __restrict__ b1,
    const float* __restrict__ W2, const float* __restrict__ b2,
    float* __restrict__ out)
{
    const int lane = threadIdx.x & 63;
    const int b    = blockIdx.x * 4 + (threadIdx.x >> 6);

    const int gate = lane & 3;
    const int k    = lane >> 2;
    const int row  = gate * 16 + k;

    const float wih  = W_ih_f[row];
    const float bias = b_ih_f[row] + b_hh_f[row];
    float w0  = W_hh_f[row*16+ 0], w1  = W_hh_f[row*16+ 1], w2  = W_hh_f[row*16+ 2], w3  = W_hh_f[row*16+ 3];
    float w4  = W_hh_f[row*16+ 4], w5  = W_hh_f[row*16+ 5], w6  = W_hh_f[row*16+ 6], w7  = W_hh_f[row*16+ 7];
    float w8  = W_hh_f[row*16+ 8], w9  = W_hh_f[row*16+ 9], w10 = W_hh_f[row*16+10], w11 = W_hh_f[row*16+11];
    float w12 = W_hh_f[row*16+12], w13 = W_hh_f[row*16+13], w14 = W_hh_f[row*16+14], w15 = W_hh_f[row*16+15];

    float xv[8];
#pragma unroll
    for (int i = 0; i < 8; ++i) xv[i] = x[b * T_LEN + i * 64 + lane];

    // per-lane activation constants: sigmoid for i/f/o, tanh (=2*sig(2x)-1) for g
    const bool  isg = (gate == 2);
    const float c1  = isg ? (-2.0f * LOG2E) : (-LOG2E);
    const float cm  = isg ? 2.0f : 1.0f;
    const float ca  = isg ? -1.0f : 0.0f;
    const float k2  = -2.0f * LOG2E;

    // hidden state lives in SGPRs (wave-uniform), cell state per-lane (gate0 role)
    float h0=0.f,h1=0.f,h2=0.f,h3=0.f,h4=0.f,h5=0.f,h6=0.f,h7=0.f;
    float h8=0.f,h9=0.f,h10=0.f,h11=0.f,h12=0.f,h13=0.f,h14=0.f,h15=0.f;
    float c = 0.0f;

#pragma unroll
    for (int i = 0; i < 8; ++i) {
        float xc = xv[i];
        asm volatile(
            "s_mov_b32 s20, 0\n\t"
            "1:\n\t"
            // xs = x[t] broadcast; start both matvec chains
            "v_readlane_b32 s21, %[xc], s20\n\t"
            "v_mul_f32  v21, %[h0], %[w0]\n\t"
            "v_fmac_f32 v21, %[h1], %[w1]\n\t"
            "v_fma_f32  v20, s21, %[wih], %[bias]\n\t"
            "v_fmac_f32 v21, %[h2], %[w2]\n\t"
            "v_fmac_f32 v20, %[h8], %[w8]\n\t"
            "v_fmac_f32 v21, %[h3], %[w3]\n\t"
            "v_fmac_f32 v20, %[h9], %[w9]\n\t"
            "v_fmac_f32 v21, %[h4], %[w4]\n\t"
            "v_fmac_f32 v20, %[h10], %[w10]\n\t"
            "v_fmac_f32 v21, %[h5], %[w5]\n\t"
            "v_fmac_f32 v20, %[h11], %[w11]\n\t"
            "v_fmac_f32 v21, %[h6], %[w6]\n\t"
            "v_fmac_f32 v20, %[h12], %[w12]\n\t"
            "v_fmac_f32 v21, %[h7], %[w7]\n\t"
            "v_fmac_f32 v20, %[h13], %[w13]\n\t"
            "v_fmac_f32 v20, %[h14], %[w14]\n\t"
            "v_fmac_f32 v20, %[h15], %[w15]\n\t"
            "v_add_f32 v20, v20, v21\n\t"          // z
            // act = sigmoid/tanh(z) per lane role  (TRANS hazard: 2 waits each)
            "v_mul_f32 v22, v20, %[c1]\n\t"
            "v_exp_f32 v22, v22\n\t"
            "s_add_u32 s20, s20, 1\n\t"            // fill trans wait slot
            "s_nop 0\n\t"
            "v_add_f32 v22, 1.0, v22\n\t"
            "v_rcp_f32 v22, v22\n\t"
            "s_nop 1\n\t"
            "v_fma_f32 v23, v22, %[cm], %[ca]\n\t" // act
            "s_nop 2\n\t"                           // VALU->DPP-src hazard
            "v_mov_b32_dpp v24, v23 quad_perm:[1,0,3,2] row_mask:0xf bank_mask:0xf\n\t" // f
            "v_mov_b32_dpp v25, v23 quad_perm:[2,3,0,1] row_mask:0xf bank_mask:0xf\n\t" // g
            "v_mov_b32_dpp v26, v23 quad_perm:[3,2,1,0] row_mask:0xf bank_mask:0xf\n\t" // o
            // c = f*c + i*g ; th = tanh(c) ; h = o*th   (valid on gate0 lanes)
            "v_mul_f32 v27, v23, v25\n\t"
            "v_fma_f32 %[c], v24, %[c], v27\n\t"
            "v_mul_f32 v22, %[k2], %[c]\n\t"
            "v_exp_f32 v22, v22\n\t"
            "s_cmp_lt_u32 s20, 64\n\t"             // fill trans wait slot (scc safe below)
            "s_nop 0\n\t"
            "v_add_f32 v22, 1.0, v22\n\t"
            "v_rcp_f32 v22, v22\n\t"
            "s_nop 1\n\t"
            "v_fma_f32 v22, v22, 2.0, -1.0\n\t"
            "v_mul_f32 v28, v26, v22\n\t"
            "s_nop 1\n\t"                           // VALU->readlane-src hazard
            // broadcast h[k] (lane 4k) into SGPRs for next step
            "v_readlane_b32 %[h0],  v28, 0\n\t"
            "v_readlane_b32 %[h1],  v28, 4\n\t"
            "v_readlane_b32 %[h2],  v28, 8\n\t"
            "v_readlane_b32 %[h3],  v28, 12\n\t"
            "v_readlane_b32 %[h4],  v28, 16\n\t"
            "v_readlane_b32 %[h5],  v28, 20\n\t"
            "v_readlane_b32 %[h6],  v28, 24\n\t"
            "v_readlane_b32 %[h7],  v28, 28\n\t"
            "v_readlane_b32 %[h8],  v28, 32\n\t"
            "v_readlane_b32 %[h9],  v28, 36\n\t"
            "v_readlane_b32 %[h10], v28, 40\n\t"
            "v_readlane_b32 %[h11], v28, 44\n\t"
            "v_readlane_b32 %[h12], v28, 48\n\t"
            "v_readlane_b32 %[h13], v28, 52\n\t"
            "v_readlane_b32 %[h14], v28, 56\n\t"
            "v_readlane_b32 %[h15], v28, 60\n\t"
            "s_cbranch_scc1 1b\n\t"
            "s_nop 3\n\t"                           // protect compiler-side h reads
            : [h0]"+s"(h0), [h1]"+s"(h1), [h2]"+s"(h2), [h3]"+s"(h3),
              [h4]"+s"(h4), [h5]"+s"(h5), [h6]"+s"(h6), [h7]"+s"(h7),
              [h8]"+s"(h8), [h9]"+s"(h9), [h10]"+s"(h10), [h11]"+s"(h11),
              [h12]"+s"(h12), [h13]"+s"(h13), [h14]"+s"(h14), [h15]"+s"(h15),
              [c]"+v"(c)
            : [xc]"v"(xc), [wih]"v"(wih), [bias]"v"(bias),
              [c1]"v"(c1), [cm]"v"(cm), [ca]"v"(ca), [k2]"v"(k2),
              [w0]"v"(w0), [w1]"v"(w1), [w2]"v"(w2), [w3]"v"(w3),
              [w4]"v"(w4), [w5]"v"(w5), [w6]"v"(w6), [w7]"v"(w7),
              [w8]"v"(w8), [w9]"v"(w9), [w10]"v"(w10), [w11]"v"(w11),
              [w12]"v"(w12), [w13]"v"(w13), [w14]"v"(w14), [w15]"v"(w15)
            : "v20","v21","v22","v23","v24","v25","v26","v27","v28",
              "s20","s21","scc");
    }

    float hs[16] = {h0,h1,h2,h3,h4,h5,h6,h7,h8,h9,h10,h11,h12,h13,h14,h15};

    // ---- reverse direction: single LSTM step on x[:, T-1] from zero state ----
    const float wihr  = W_ih_r[row];
    const float biasr = b_ih_r[row] + b_hh_r[row];
    const float xlast = rl(xv[7], 63);

    const float zr   = fmaf(xlast, wihr, biasr);
    const float er   = __builtin_amdgcn_exp2f(zr * c1);
    const float rr_  = __builtin_amdgcn_rcpf(1.0f + er);
    const float actr = fmaf(rr_, cm, ca);
    const float gr   = qperm<0x4E>(actr);
    const float or_  = qperm<0x1B>(actr);
    const float cr   = actr * gr;                      // sig(i)*tanh(g), c0 = 0
    const float e2r  = __builtin_amdgcn_exp2f(cr * (-2.0f * LOG2E));
    const float thr_ = fmaf(__builtin_amdgcn_rcpf(1.0f + e2r), 2.0f, -1.0f);
    const float hbw  = or_ * thr_;

    float hr[16];
#pragma unroll
    for (int n = 0; n < 16; ++n) hr[n] = rl(hbw, 4 * n);

    // ---- MLP head: hid = LeakyReLU([h_fwd, h_bwd] @ W1.T + b1); out = hid @ W2.T + b2
    const int m = lane & 15;       // all 4 groups compute identical hid[m]
    float hid = b1[m];
#pragma unroll
    for (int n = 0; n < 16; ++n) hid = fmaf(hs[n], W1[m * 32 + n], hid);
#pragma unroll
    for (int n = 0; n < 16; ++n) hid = fmaf(hr[n], W1[m * 32 + 16 + n], hid);
    hid = (hid > 0.0f) ? hid : (0.2f * hid);

    float v = hid * W2[m];
    v += __shfl_xor(v, 1);
    v += __shfl_xor(v, 2);
    v += __shfl_xor(v, 4);
    v += __shfl_xor(v, 8);
    if (lane == 0) out[b] = v + b2[0];
}

extern "C" void kernel_launch(void* const* d_in, const int* in_sizes, int n_in,
                              void* d_out, int out_size, void* d_ws, size_t ws_size,
                              hipStream_t stream) {
    const float* x      = (const float*)d_in[0];
    const float* W_ih_f = (const float*)d_in[1];
    const float* W_hh_f = (const float*)d_in[2];
    const float* b_ih_f = (const float*)d_in[3];
    const float* b_hh_f = (const float*)d_in[4];
    const float* W_ih_r = (const float*)d_in[5];
    const float* W_hh_r = (const float*)d_in[6];
    const float* b_ih_r = (const float*)d_in[7];
    const float* b_hh_r = (const float*)d_in[8];
    const float* W1     = (const float*)d_in[9];
    const float* b1     = (const float*)d_in[10];
    const float* W2     = (const float*)d_in[11];
    const float* b2     = (const float*)d_in[12];
    float* out = (float*)d_out;

    const int B = in_sizes[0] / T_LEN;   // 2048
    dim3 grid(B / 4), block(256);
    hipLaunchKernelGGL(bilstm_head_kernel, grid, block, 0, stream,
                       x, W_ih_f, W_hh_f, b_ih_f, b_hh_f,
                       W_ih_r, W_hh_r, b_ih_r, b_hh_r,
                       W1, b1, W2, b2, out);
}

// Round 5
// 103.502 us; speedup vs baseline: 1.1028x; 1.1028x over previous
//
#include <hip/hip_runtime.h>

#define T_LEN 512
#define LOG2E 1.4426950408889634f

typedef float f32x2 __attribute__((ext_vector_type(2)));

// readlane: broadcast from a lane into a wave-uniform (SGPR) value
__device__ __forceinline__ float rl(float v, int lane) {
    return __int_as_float(__builtin_amdgcn_readlane(__float_as_int(v), lane));
}

// quad_perm DPP (C-side epilogue use)
template<int CTRL>
__device__ __forceinline__ float qperm(float v) {
    return __int_as_float(__builtin_amdgcn_mov_dpp(__float_as_int(v), CTRL, 0xF, 0xF, true));
}

// Layout: one 64-lane wave per batch element.
// lane l -> gate g = l&3 (0:i 1:f 2:g 3:o), hidden k = l>>2; weight row = g*16+k.
// asm inner loop, v4: v_pk_fma_f32 matvec (h in pinned SGPR pairs s[40:55],
// W prescaled by the per-lane activation constant c1 so z*c1 falls out of the
// matvec directly), trimmed hazard nops, loop SALU fills TRANS wait slots.
__global__ __launch_bounds__(256, 2) void bilstm_head_kernel(
    const float* __restrict__ x,
    const float* __restrict__ W_ih_f, const float* __restrict__ W_hh_f,
    const float* __restrict__ b_ih_f, const float* __restrict__ b_hh_f,
    const float* __restrict__ W_ih_r, const float* __restrict__ W_hh_r,
    const float* __restrict__ b_ih_r, const float* __restrict__ b_hh_r,
    const float* __restrict__ W1, const float* __restrict__ b1,
    const float* __restrict__ W2, const float* __restrict__ b2,
    float* __restrict__ out)
{
    const int lane = threadIdx.x & 63;
    const int b    = blockIdx.x * 4 + (threadIdx.x >> 6);

    const int gate = lane & 3;
    const int k    = lane >> 2;
    const int row  = gate * 16 + k;

    // per-lane activation constants: sigmoid for i/f/o, tanh (=2*sig(2x)-1) for g
    const bool  isg = (gate == 2);
    const float c1  = isg ? (-2.0f * LOG2E) : (-LOG2E);
    const float cm  = isg ? 2.0f : 1.0f;
    const float ca  = isg ? -1.0f : 0.0f;
    const float k2  = -2.0f * LOG2E;

    // forward weights prescaled by c1: matvec then directly feeds exp2
    const float wih_p  = W_ih_f[row] * c1;
    const float bias_p = (b_ih_f[row] + b_hh_f[row]) * c1;
    f32x2 wp[8];
#pragma unroll
    for (int n = 0; n < 8; ++n) {
        wp[n].x = W_hh_f[row * 16 + 2 * n]     * c1;
        wp[n].y = W_hh_f[row * 16 + 2 * n + 1] * c1;
    }

    float xv[8];
#pragma unroll
    for (int i = 0; i < 8; ++i) xv[i] = x[b * T_LEN + i * 64 + lane];

    // hidden state as 8 wave-uniform SGPR pairs, cell state per-lane
    f32x2 h01 = {0,0}, h23 = {0,0}, h45 = {0,0}, h67 = {0,0};
    f32x2 h89 = {0,0}, hAB = {0,0}, hCD = {0,0}, hEF = {0,0};
    float c = 0.0f;

#pragma unroll
    for (int i = 0; i < 8; ++i) {
        float xc = xv[i];
        asm volatile(
            // stage h pairs into pinned s[40:55] for the pk_fma loop
            "s_mov_b64 s[40:41], %[h01]\n\t"
            "s_mov_b64 s[42:43], %[h23]\n\t"
            "s_mov_b64 s[44:45], %[h45]\n\t"
            "s_mov_b64 s[46:47], %[h67]\n\t"
            "s_mov_b64 s[48:49], %[h89]\n\t"
            "s_mov_b64 s[50:51], %[hAB]\n\t"
            "s_mov_b64 s[52:53], %[hCD]\n\t"
            "s_mov_b64 s[54:55], %[hEF]\n\t"
            "s_mov_b32 s21, 0\n\t"
            "1:\n\t"
            "v_readlane_b32 s22, %[xc], s21\n\t"
            "s_add_u32 s21, s21, 1\n\t"          // fills readlane->SGPR-read slot 1
            "v_mov_b32 v21, 0\n\t"               // slot 2
            "v_fma_f32 v20, s22, %[wih], %[bias]\n\t"
            // z*c1 via 8 packed dual-fp32 FMAs (h = scalar pair operand)
            "v_pk_fma_f32 v[20:21], s[40:41], %[w01], v[20:21]\n\t"
            "v_pk_fma_f32 v[20:21], s[42:43], %[w23], v[20:21]\n\t"
            "v_pk_fma_f32 v[20:21], s[44:45], %[w45], v[20:21]\n\t"
            "v_pk_fma_f32 v[20:21], s[46:47], %[w67], v[20:21]\n\t"
            "v_pk_fma_f32 v[20:21], s[48:49], %[w89], v[20:21]\n\t"
            "v_pk_fma_f32 v[20:21], s[50:51], %[wAB], v[20:21]\n\t"
            "v_pk_fma_f32 v[20:21], s[52:53], %[wCD], v[20:21]\n\t"
            "v_pk_fma_f32 v[20:21], s[54:55], %[wEF], v[20:21]\n\t"
            "v_add_f32 v20, v20, v21\n\t"        // = c1*z (prescaled)
            "v_exp_f32 v22, v20\n\t"
            "s_cmp_lt_u32 s21, 64\n\t"           // trans wait slot 1 (scc->branch)
            "s_nop 0\n\t"                        // slot 2
            "v_add_f32 v22, 1.0, v22\n\t"
            "v_rcp_f32 v22, v22\n\t"
            "s_nop 1\n\t"
            "v_fma_f32 v23, v22, %[cm], %[ca]\n\t" // act
            "s_nop 1\n\t"                        // VALU->DPP-src (2 states)
            "v_mov_b32_dpp v24, v23 quad_perm:[1,0,3,2] row_mask:0xf bank_mask:0xf\n\t" // f
            "v_mov_b32_dpp v25, v23 quad_perm:[2,3,0,1] row_mask:0xf bank_mask:0xf\n\t" // g
            "v_mov_b32_dpp v26, v23 quad_perm:[3,2,1,0] row_mask:0xf bank_mask:0xf\n\t" // o
            "v_mul_f32 v27, v23, v25\n\t"
            "v_fma_f32 %[c], v24, %[c], v27\n\t" // c = f*c + i*g
            "v_mul_f32 v22, %[k2], %[c]\n\t"
            "v_exp_f32 v22, v22\n\t"
            "s_nop 1\n\t"
            "v_add_f32 v22, 1.0, v22\n\t"
            "v_rcp_f32 v22, v22\n\t"
            "s_nop 1\n\t"
            "v_fma_f32 v22, v22, 2.0, -1.0\n\t"  // tanh(c)
            "v_mul_f32 v28, v26, v22\n\t"        // h on lanes 4k
            "s_nop 0\n\t"                        // VALU->readlane-src
            "v_readlane_b32 s40, v28, 0\n\t"
            "v_readlane_b32 s41, v28, 4\n\t"
            "v_readlane_b32 s42, v28, 8\n\t"
            "v_readlane_b32 s43, v28, 12\n\t"
            "v_readlane_b32 s44, v28, 16\n\t"
            "v_readlane_b32 s45, v28, 20\n\t"
            "v_readlane_b32 s46, v28, 24\n\t"
            "v_readlane_b32 s47, v28, 28\n\t"
            "v_readlane_b32 s48, v28, 32\n\t"
            "v_readlane_b32 s49, v28, 36\n\t"
            "v_readlane_b32 s50, v28, 40\n\t"
            "v_readlane_b32 s51, v28, 44\n\t"
            "v_readlane_b32 s52, v28, 48\n\t"
            "v_readlane_b32 s53, v28, 52\n\t"
            "v_readlane_b32 s54, v28, 56\n\t"
            "v_readlane_b32 s55, v28, 60\n\t"
            "s_cbranch_scc1 1b\n\t"
            "s_nop 2\n\t"                        // readlane->SALU-read guard
            "s_mov_b64 %[h01], s[40:41]\n\t"
            "s_mov_b64 %[h23], s[42:43]\n\t"
            "s_mov_b64 %[h45], s[44:45]\n\t"
            "s_mov_b64 %[h67], s[46:47]\n\t"
            "s_mov_b64 %[h89], s[48:49]\n\t"
            "s_mov_b64 %[hAB], s[50:51]\n\t"
            "s_mov_b64 %[hCD], s[52:53]\n\t"
            "s_mov_b64 %[hEF], s[54:55]\n\t"
            : [h01]"+s"(h01), [h23]"+s"(h23), [h45]"+s"(h45), [h67]"+s"(h67),
              [h89]"+s"(h89), [hAB]"+s"(hAB), [hCD]"+s"(hCD), [hEF]"+s"(hEF),
              [c]"+v"(c)
            : [xc]"v"(xc), [wih]"v"(wih_p), [bias]"v"(bias_p),
              [cm]"v"(cm), [ca]"v"(ca), [k2]"v"(k2),
              [w01]"v"(wp[0]), [w23]"v"(wp[1]), [w45]"v"(wp[2]), [w67]"v"(wp[3]),
              [w89]"v"(wp[4]), [wAB]"v"(wp[5]), [wCD]"v"(wp[6]), [wEF]"v"(wp[7])
            : "v20","v21","v22","v23","v24","v25","v26","v27","v28",
              "s21","s22","s40","s41","s42","s43","s44","s45","s46","s47",
              "s48","s49","s50","s51","s52","s53","s54","s55","scc");
    }

    float hs[16] = {h01.x,h01.y,h23.x,h23.y,h45.x,h45.y,h67.x,h67.y,
                    h89.x,h89.y,hAB.x,hAB.y,hCD.x,hCD.y,hEF.x,hEF.y};

    // ---- reverse direction: single LSTM step on x[:, T-1] from zero state ----
    const float wihr  = W_ih_r[row];
    const float biasr = b_ih_r[row] + b_hh_r[row];
    const float xlast = rl(xv[7], 63);

    const float zr   = fmaf(xlast, wihr, biasr);
    const float er   = __builtin_amdgcn_exp2f(zr * c1);
    const float rr_  = __builtin_amdgcn_rcpf(1.0f + er);
    const float actr = fmaf(rr_, cm, ca);
    const float gr   = qperm<0x4E>(actr);
    const float or_  = qperm<0x1B>(actr);
    const float cr   = actr * gr;                      // sig(i)*tanh(g), c0 = 0
    const float e2r  = __builtin_amdgcn_exp2f(cr * (-2.0f * LOG2E));
    const float thr_ = fmaf(__builtin_amdgcn_rcpf(1.0f + e2r), 2.0f, -1.0f);
    const float hbw  = or_ * thr_;

    float hr[16];
#pragma unroll
    for (int n = 0; n < 16; ++n) hr[n] = rl(hbw, 4 * n);

    // ---- MLP head: hid = LeakyReLU([h_fwd, h_bwd] @ W1.T + b1); out = hid @ W2.T + b2
    const int m = lane & 15;       // all 4 groups compute identical hid[m]
    float hid = b1[m];
#pragma unroll
    for (int n = 0; n < 16; ++n) hid = fmaf(hs[n], W1[m * 32 + n], hid);
#pragma unroll
    for (int n = 0; n < 16; ++n) hid = fmaf(hr[n], W1[m * 32 + 16 + n], hid);
    hid = (hid > 0.0f) ? hid : (0.2f * hid);

    float v = hid * W2[m];
    v += __shfl_xor(v, 1);
    v += __shfl_xor(v, 2);
    v += __shfl_xor(v, 4);
    v += __shfl_xor(v, 8);
    if (lane == 0) out[b] = v + b2[0];
}

extern "C" void kernel_launch(void* const* d_in, const int* in_sizes, int n_in,
                              void* d_out, int out_size, void* d_ws, size_t ws_size,
                              hipStream_t stream) {
    const float* x      = (const float*)d_in[0];
    const float* W_ih_f = (const float*)d_in[1];
    const float* W_hh_f = (const float*)d_in[2];
    const float* b_ih_f = (const float*)d_in[3];
    const float* b_hh_f = (const float*)d_in[4];
    const float* W_ih_r = (const float*)d_in[5];
    const float* W_hh_r = (const float*)d_in[6];
    const float* b_ih_r = (const float*)d_in[7];
    const float* b_hh_r = (const float*)d_in[8];
    const float* W1     = (const float*)d_in[9];
    const float* b1     = (const float*)d_in[10];
    const float* W2     = (const float*)d_in[11];
    const float* b2     = (const float*)d_in[12];
    float* out = (float*)d_out;

    const int B = in_sizes[0] / T_LEN;   // 2048
    dim3 grid(B / 4), block(256);
    hipLaunchKernelGGL(bilstm_head_kernel, grid, block, 0, stream,
                       x, W_ih_f, W_hh_f, b_ih_f, b_hh_f,
                       W_ih_r, W_hh_r, b_ih_r, b_hh_r,
                       W1, b1, W2, b2, out);
}

// Round 6
// 94.682 us; speedup vs baseline: 1.2055x; 1.0932x over previous
//
#include <hip/hip_runtime.h>

#define T_LEN 512
#define LOG2E 1.4426950408889634f

typedef float f32x2 __attribute__((ext_vector_type(2)));

__device__ __forceinline__ float rl(float v, int lane) {
    return __int_as_float(__builtin_amdgcn_readlane(__float_as_int(v), lane));
}
template<int CTRL>
__device__ __forceinline__ float qperm(float v) {
    return __int_as_float(__builtin_amdgcn_mov_dpp(__float_as_int(v), CTRL, 0xF, 0xF, true));
}

// One 64-lane wave per batch element. lane l -> gate g=l&3, hidden k=l>>2,
// weight row = g*16+k. v5: h/x broadcast via per-wave LDS region instead of
// v_readlane: all lanes ds_write_b32 h-candidate to row*4 (only rows 0..15 =
// gate-0 region is read back; other rows land in dead regions), then 4 uniform
// ds_read_b128 rebuild h pairs for the pk_fma matvec. x staged in LDS once,
// one uniform ds_read_b32 per step prefetched in the trans-hazard shadow.
// Per-wave LDS: 592 floats (h 0..63 | x 64..575 | pad 576..591).
__global__ __launch_bounds__(256, 2) void bilstm_head_kernel(
    const float* __restrict__ x,
    const float* __restrict__ W_ih_f, const float* __restrict__ W_hh_f,
    const float* __restrict__ b_ih_f, const float* __restrict__ b_hh_f,
    const float* __restrict__ W_ih_r, const float* __restrict__ W_hh_r,
    const float* __restrict__ b_ih_r, const float* __restrict__ b_hh_r,
    const float* __restrict__ W1, const float* __restrict__ b1,
    const float* __restrict__ W2, const float* __restrict__ b2,
    float* __restrict__ out)
{
    extern __shared__ float smem[];          // 4 waves * 592 floats

    const int tid  = threadIdx.x;
    const int wid  = tid >> 6;
    const int lane = tid & 63;
    const int b    = blockIdx.x * 4 + wid;

    const int gate = lane & 3;
    const int k    = lane >> 2;
    const int row  = gate * 16 + k;

    const bool  isg = (gate == 2);
    const float c1  = isg ? (-2.0f * LOG2E) : (-LOG2E);
    const float cm  = isg ? 2.0f : 1.0f;
    const float ca  = isg ? -1.0f : 0.0f;
    const float k2  = -2.0f * LOG2E;

    // weights prescaled by c1 so the matvec result feeds v_exp directly
    const float wih_p  = W_ih_f[row] * c1;
    const float bias_p = (b_ih_f[row] + b_hh_f[row]) * c1;
    f32x2 wp[8];
#pragma unroll
    for (int n = 0; n < 8; ++n) {
        wp[n].x = W_hh_f[row * 16 + 2 * n]     * c1;
        wp[n].y = W_hh_f[row * 16 + 2 * n + 1] * c1;
    }

    const int wfl = wid * 592;               // wave base (floats)
    // stage this batch's x row into LDS (coalesced, wave-private region)
#pragma unroll
    for (int i = 0; i < 8; ++i)
        smem[wfl + 64 + i * 64 + lane] = x[b * T_LEN + i * 64 + lane];

    const unsigned hbase = (unsigned)(wfl * 4);      // LDS byte offsets
    unsigned xaddr = hbase + 224;                    // x base - 32 (pre-bump)
    const unsigned waddr = hbase + (unsigned)(row * 4);
    float c = 0.0f;

// one LSTM step: consume x in XC, prefetch next x into XN at offset XOFF
#define LSTM_STEP(XC, XN, XOFF) \
    "s_waitcnt lgkmcnt(0)\n\t" \
    "v_fma_f32 v20, " XC ", %[wih], %[bias]\n\t" \
    "v_mov_b32 v21, 0\n\t" \
    "v_pk_mul_f32 v[24:25], v[40:41], %[w89]\n\t" \
    "v_pk_fma_f32 v[20:21], v[32:33], %[w01], v[20:21]\n\t" \
    "v_pk_fma_f32 v[24:25], v[42:43], %[wAB], v[24:25]\n\t" \
    "v_pk_fma_f32 v[20:21], v[34:35], %[w23], v[20:21]\n\t" \
    "v_pk_fma_f32 v[24:25], v[44:45], %[wCD], v[24:25]\n\t" \
    "v_pk_fma_f32 v[20:21], v[36:37], %[w45], v[20:21]\n\t" \
    "v_pk_fma_f32 v[24:25], v[46:47], %[wEF], v[24:25]\n\t" \
    "v_pk_fma_f32 v[20:21], v[38:39], %[w67], v[20:21]\n\t" \
    "v_add_f32 v20, v20, v24\n\t" \
    "v_add_f32 v21, v21, v25\n\t" \
    "v_add_f32 v20, v20, v21\n\t" \
    "v_exp_f32 v22, v20\n\t" \
    "ds_read_b32 " XN ", %[vX] offset:" XOFF "\n\t" \
    "s_nop 0\n\t" \
    "v_add_f32 v22, 1.0, v22\n\t" \
    "v_rcp_f32 v22, v22\n\t" \
    "s_nop 1\n\t" \
    "v_fma_f32 v23, v22, %[cm], %[ca]\n\t" \
    "s_nop 1\n\t" \
    "v_mov_b32_dpp v26, v23 quad_perm:[1,0,3,2] row_mask:0xf bank_mask:0xf\n\t" \
    "v_mov_b32_dpp v27, v23 quad_perm:[2,3,0,1] row_mask:0xf bank_mask:0xf\n\t" \
    "v_mov_b32_dpp v28, v23 quad_perm:[3,2,1,0] row_mask:0xf bank_mask:0xf\n\t" \
    "v_mul_f32 v22, v23, v27\n\t" \
    "v_fma_f32 %[c], v26, %[c], v22\n\t" \
    "v_mul_f32 v22, %[k2], %[c]\n\t" \
    "v_exp_f32 v22, v22\n\t" \
    "s_nop 1\n\t" \
    "v_add_f32 v22, 1.0, v22\n\t" \
    "v_rcp_f32 v22, v22\n\t" \
    "s_nop 1\n\t" \
    "v_fma_f32 v22, v22, 2.0, -1.0\n\t" \
    "v_mul_f32 v29, v28, v22\n\t" \
    "ds_write_b32 %[vW], v29\n\t" \
    "s_waitcnt lgkmcnt(0)\n\t" \
    "ds_read_b128 v[32:35], %[vB] offset:0\n\t" \
    "ds_read_b128 v[36:39], %[vB] offset:16\n\t" \
    "ds_read_b128 v[40:43], %[vB] offset:32\n\t" \
    "ds_read_b128 v[44:47], %[vB] offset:48\n\t"

    asm volatile(
        // h = 0 in pair regs v[32:47]; prefetch x_0; loop counter
        "v_mov_b32 v32, 0\n\t" "v_mov_b32 v33, 0\n\t"
        "v_mov_b32 v34, 0\n\t" "v_mov_b32 v35, 0\n\t"
        "v_mov_b32 v36, 0\n\t" "v_mov_b32 v37, 0\n\t"
        "v_mov_b32 v38, 0\n\t" "v_mov_b32 v39, 0\n\t"
        "v_mov_b32 v40, 0\n\t" "v_mov_b32 v41, 0\n\t"
        "v_mov_b32 v42, 0\n\t" "v_mov_b32 v43, 0\n\t"
        "v_mov_b32 v44, 0\n\t" "v_mov_b32 v45, 0\n\t"
        "v_mov_b32 v46, 0\n\t" "v_mov_b32 v47, 0\n\t"
        "ds_read_b32 v30, %[vB] offset:256\n\t"
        "s_mov_b32 s20, 0\n\t"
        "1:\n\t"
        "v_add_u32 %[vX], 32, %[vX]\n\t"
        LSTM_STEP("v30", "v31", "4")
        LSTM_STEP("v31", "v30", "8")
        LSTM_STEP("v30", "v31", "12")
        LSTM_STEP("v31", "v30", "16")
        LSTM_STEP("v30", "v31", "20")
        LSTM_STEP("v31", "v30", "24")
        LSTM_STEP("v30", "v31", "28")
        LSTM_STEP("v31", "v30", "32")
        "s_add_u32 s20, s20, 1\n\t"
        "s_cmp_lt_u32 s20, 64\n\t"
        "s_cbranch_scc1 1b\n\t"
        : [c]"+v"(c), [vX]"+v"(xaddr)
        : [vB]"v"(hbase), [vW]"v"(waddr),
          [wih]"v"(wih_p), [bias]"v"(bias_p),
          [cm]"v"(cm), [ca]"v"(ca), [k2]"v"(k2),
          [w01]"v"(wp[0]), [w23]"v"(wp[1]), [w45]"v"(wp[2]), [w67]"v"(wp[3]),
          [w89]"v"(wp[4]), [wAB]"v"(wp[5]), [wCD]"v"(wp[6]), [wEF]"v"(wp[7])
        : "v20","v21","v22","v23","v24","v25","v26","v27","v28","v29",
          "v30","v31","v32","v33","v34","v35","v36","v37","v38","v39",
          "v40","v41","v42","v43","v44","v45","v46","v47",
          "s20","scc","memory");
#undef LSTM_STEP

    // final forward hidden state sits in LDS gate-0 region
    float hs[16];
#pragma unroll
    for (int n = 0; n < 16; ++n) hs[n] = smem[wfl + n];

    // ---- reverse direction: single LSTM step on x[:, T-1] from zero state ----
    const float wihr  = W_ih_r[row];
    const float biasr = b_ih_r[row] + b_hh_r[row];
    const float xlast = smem[wfl + 64 + 511];

    const float zr   = fmaf(xlast, wihr, biasr);
    const float er   = __builtin_amdgcn_exp2f(zr * c1);
    const float rr_  = __builtin_amdgcn_rcpf(1.0f + er);
    const float actr = fmaf(rr_, cm, ca);
    const float gr   = qperm<0x4E>(actr);
    const float or_  = qperm<0x1B>(actr);
    const float cr   = actr * gr;                      // sig(i)*tanh(g), c0 = 0
    const float e2r  = __builtin_amdgcn_exp2f(cr * (-2.0f * LOG2E));
    const float thr_ = fmaf(__builtin_amdgcn_rcpf(1.0f + e2r), 2.0f, -1.0f);
    const float hbw  = or_ * thr_;

    float hr[16];
#pragma unroll
    for (int n = 0; n < 16; ++n) hr[n] = rl(hbw, 4 * n);

    // ---- MLP head: hid = LeakyReLU([h_fwd, h_bwd] @ W1.T + b1); out = hid @ W2.T + b2
    const int m = lane & 15;
    float hid = b1[m];
#pragma unroll
    for (int n = 0; n < 16; ++n) hid = fmaf(hs[n], W1[m * 32 + n], hid);
#pragma unroll
    for (int n = 0; n < 16; ++n) hid = fmaf(hr[n], W1[m * 32 + 16 + n], hid);
    hid = (hid > 0.0f) ? hid : (0.2f * hid);

    float v = hid * W2[m];
    v += __shfl_xor(v, 1);
    v += __shfl_xor(v, 2);
    v += __shfl_xor(v, 4);
    v += __shfl_xor(v, 8);
    if (lane == 0) out[b] = v + b2[0];
}

extern "C" void kernel_launch(void* const* d_in, const int* in_sizes, int n_in,
                              void* d_out, int out_size, void* d_ws, size_t ws_size,
                              hipStream_t stream) {
    const float* x      = (const float*)d_in[0];
    const float* W_ih_f = (const float*)d_in[1];
    const float* W_hh_f = (const float*)d_in[2];
    const float* b_ih_f = (const float*)d_in[3];
    const float* b_hh_f = (const float*)d_in[4];
    const float* W_ih_r = (const float*)d_in[5];
    const float* W_hh_r = (const float*)d_in[6];
    const float* b_ih_r = (const float*)d_in[7];
    const float* b_hh_r = (const float*)d_in[8];
    const float* W1     = (const float*)d_in[9];
    const float* b1     = (const float*)d_in[10];
    const float* W2     = (const float*)d_in[11];
    const float* b2     = (const float*)d_in[12];
    float* out = (float*)d_out;

    const int B = in_sizes[0] / T_LEN;   // 2048
    dim3 grid(B / 4), block(256);
    size_t lds_bytes = 4 * 592 * sizeof(float);   // 9472 B/block
    hipLaunchKernelGGL(bilstm_head_kernel, grid, block, lds_bytes, stream,
                       x, W_ih_f, W_hh_f, b_ih_f, b_hh_f,
                       W_ih_r, W_hh_r, b_ih_r, b_hh_r,
                       W1, b1, W2, b2, out);
}

// Round 7
// 82.385 us; speedup vs baseline: 1.3854x; 1.1493x over previous
//
#include <hip/hip_runtime.h>

#define T_LEN 512
#define LOG2E 1.4426950408889634f

typedef float f32x2 __attribute__((ext_vector_type(2)));

__device__ __forceinline__ float rl(float v, int lane) {
    return __int_as_float(__builtin_amdgcn_readlane(__float_as_int(v), lane));
}
template<int CTRL>
__device__ __forceinline__ float qperm(float v) {
    return __int_as_float(__builtin_amdgcn_mov_dpp(__float_as_int(v), CTRL, 0xF, 0xF, true));
}

// One 64-lane wave per batch element. lane l -> gate g=l&3, hidden k=l>>2,
// weight row = g*16+k. v6: single LDS round trip per step -- ds_write h then
// 4x ds_read_b128 issued back-to-back with NO intervening wait (same-wave DS
// ops execute in order); next step's head uses staggered partial lgkmcnt
// waits (x, write, r1..r4 return in order) so the matvec starts on first
// arrival. Per-wave LDS: 592 floats (h 0..63 | x 64..575 | pad 576..591).
__global__ __launch_bounds__(256, 2) void bilstm_head_kernel(
    const float* __restrict__ x,
    const float* __restrict__ W_ih_f, const float* __restrict__ W_hh_f,
    const float* __restrict__ b_ih_f, const float* __restrict__ b_hh_f,
    const float* __restrict__ W_ih_r, const float* __restrict__ W_hh_r,
    const float* __restrict__ b_ih_r, const float* __restrict__ b_hh_r,
    const float* __restrict__ W1, const float* __restrict__ b1,
    const float* __restrict__ W2, const float* __restrict__ b2,
    float* __restrict__ out)
{
    extern __shared__ float smem[];          // 4 waves * 592 floats

    const int tid  = threadIdx.x;
    const int wid  = tid >> 6;
    const int lane = tid & 63;
    const int b    = blockIdx.x * 4 + wid;

    const int gate = lane & 3;
    const int k    = lane >> 2;
    const int row  = gate * 16 + k;

    const bool  isg = (gate == 2);
    const float c1  = isg ? (-2.0f * LOG2E) : (-LOG2E);
    const float cm  = isg ? 2.0f : 1.0f;
    const float ca  = isg ? -1.0f : 0.0f;
    const float k2  = -2.0f * LOG2E;

    // weights prescaled by c1 so the matvec result feeds v_exp directly
    const float wih_p  = W_ih_f[row] * c1;
    const float bias_p = (b_ih_f[row] + b_hh_f[row]) * c1;
    f32x2 wp[8];
#pragma unroll
    for (int n = 0; n < 8; ++n) {
        wp[n].x = W_hh_f[row * 16 + 2 * n]     * c1;
        wp[n].y = W_hh_f[row * 16 + 2 * n + 1] * c1;
    }

    const int wfl = wid * 592;               // wave base (floats)
    // stage this batch's x row into LDS (coalesced, wave-private region)
#pragma unroll
    for (int i = 0; i < 8; ++i)
        smem[wfl + 64 + i * 64 + lane] = x[b * T_LEN + i * 64 + lane];

    const unsigned hbase = (unsigned)(wfl * 4);      // LDS byte offsets
    unsigned xaddr = hbase + 224;                    // x base - 32 (pre-bump)
    const unsigned waddr = hbase + (unsigned)(row * 4);
    float c = 0.0f;

// one LSTM step. Outstanding DS at head (issue order): x(prev), write, r1..r4.
// In-order returns -> staggered partial waits; write+reads at tail, no wait.
#define LSTM_STEP(XC, XN, XOFF) \
    "s_waitcnt lgkmcnt(5)\n\t" \
    "v_fma_f32 v20, " XC ", %[wih], %[bias]\n\t" \
    "v_mov_b32 v21, 0\n\t" \
    "s_waitcnt lgkmcnt(3)\n\t" \
    "v_pk_fma_f32 v[20:21], v[32:33], %[w01], v[20:21]\n\t" \
    "v_pk_fma_f32 v[20:21], v[34:35], %[w23], v[20:21]\n\t" \
    "s_waitcnt lgkmcnt(2)\n\t" \
    "v_pk_fma_f32 v[20:21], v[36:37], %[w45], v[20:21]\n\t" \
    "v_pk_fma_f32 v[20:21], v[38:39], %[w67], v[20:21]\n\t" \
    "s_waitcnt lgkmcnt(1)\n\t" \
    "v_pk_mul_f32 v[24:25], v[40:41], %[w89]\n\t" \
    "v_pk_fma_f32 v[24:25], v[42:43], %[wAB], v[24:25]\n\t" \
    "s_waitcnt lgkmcnt(0)\n\t" \
    "v_pk_fma_f32 v[24:25], v[44:45], %[wCD], v[24:25]\n\t" \
    "v_pk_fma_f32 v[24:25], v[46:47], %[wEF], v[24:25]\n\t" \
    "v_add_f32 v20, v20, v24\n\t" \
    "v_add_f32 v21, v21, v25\n\t" \
    "v_add_f32 v20, v20, v21\n\t" \
    "v_exp_f32 v22, v20\n\t" \
    "ds_read_b32 " XN ", %[vX] offset:" XOFF "\n\t" \
    "s_nop 0\n\t" \
    "v_add_f32 v22, 1.0, v22\n\t" \
    "v_rcp_f32 v22, v22\n\t" \
    "s_nop 1\n\t" \
    "v_fma_f32 v23, v22, %[cm], %[ca]\n\t" \
    "s_nop 1\n\t" \
    "v_mov_b32_dpp v26, v23 quad_perm:[1,0,3,2] row_mask:0xf bank_mask:0xf\n\t" \
    "v_mov_b32_dpp v27, v23 quad_perm:[2,3,0,1] row_mask:0xf bank_mask:0xf\n\t" \
    "v_mov_b32_dpp v28, v23 quad_perm:[3,2,1,0] row_mask:0xf bank_mask:0xf\n\t" \
    "v_mul_f32 v22, v23, v27\n\t" \
    "v_fma_f32 %[c], v26, %[c], v22\n\t" \
    "v_mul_f32 v22, %[k2], %[c]\n\t" \
    "v_exp_f32 v22, v22\n\t" \
    "s_nop 1\n\t" \
    "v_add_f32 v22, 1.0, v22\n\t" \
    "v_rcp_f32 v22, v22\n\t" \
    "s_nop 1\n\t" \
    "v_fma_f32 v22, v22, 2.0, -1.0\n\t" \
    "v_mul_f32 v29, v28, v22\n\t" \
    "ds_write_b32 %[vW], v29\n\t" \
    "ds_read_b128 v[32:35], %[vB] offset:0\n\t" \
    "ds_read_b128 v[36:39], %[vB] offset:16\n\t" \
    "ds_read_b128 v[40:43], %[vB] offset:32\n\t" \
    "ds_read_b128 v[44:47], %[vB] offset:48\n\t"

    asm volatile(
        // preamble: same 6-op DS pattern as a step tail ->
        // x0 read, zero-h write, 4 h reads (return zeros)
        "v_mov_b32 v29, 0\n\t"
        "ds_read_b32 v30, %[vB] offset:256\n\t"
        "ds_write_b32 %[vW], v29\n\t"
        "ds_read_b128 v[32:35], %[vB] offset:0\n\t"
        "ds_read_b128 v[36:39], %[vB] offset:16\n\t"
        "ds_read_b128 v[40:43], %[vB] offset:32\n\t"
        "ds_read_b128 v[44:47], %[vB] offset:48\n\t"
        "s_mov_b32 s20, 0\n\t"
        "1:\n\t"
        "v_add_u32 %[vX], 32, %[vX]\n\t"
        LSTM_STEP("v30", "v31", "4")
        LSTM_STEP("v31", "v30", "8")
        LSTM_STEP("v30", "v31", "12")
        LSTM_STEP("v31", "v30", "16")
        LSTM_STEP("v30", "v31", "20")
        LSTM_STEP("v31", "v30", "24")
        LSTM_STEP("v30", "v31", "28")
        LSTM_STEP("v31", "v30", "32")
        "s_add_u32 s20, s20, 1\n\t"
        "s_cmp_lt_u32 s20, 64\n\t"
        "s_cbranch_scc1 1b\n\t"
        "s_waitcnt lgkmcnt(0)\n\t"
        : [c]"+v"(c), [vX]"+v"(xaddr)
        : [vB]"v"(hbase), [vW]"v"(waddr),
          [wih]"v"(wih_p), [bias]"v"(bias_p),
          [cm]"v"(cm), [ca]"v"(ca), [k2]"v"(k2),
          [w01]"v"(wp[0]), [w23]"v"(wp[1]), [w45]"v"(wp[2]), [w67]"v"(wp[3]),
          [w89]"v"(wp[4]), [wAB]"v"(wp[5]), [wCD]"v"(wp[6]), [wEF]"v"(wp[7])
        : "v20","v21","v22","v23","v24","v25","v26","v27","v28","v29",
          "v30","v31","v32","v33","v34","v35","v36","v37","v38","v39",
          "v40","v41","v42","v43","v44","v45","v46","v47",
          "s20","scc","memory");
#undef LSTM_STEP

    // final forward hidden state sits in LDS gate-0 region
    float hs[16];
#pragma unroll
    for (int n = 0; n < 16; ++n) hs[n] = smem[wfl + n];

    // ---- reverse direction: single LSTM step on x[:, T-1] from zero state ----
    const float wihr  = W_ih_r[row];
    const float biasr = b_ih_r[row] + b_hh_r[row];
    const float xlast = smem[wfl + 64 + 511];

    const float zr   = fmaf(xlast, wihr, biasr);
    const float er   = __builtin_amdgcn_exp2f(zr * c1);
    const float rr_  = __builtin_amdgcn_rcpf(1.0f + er);
    const float actr = fmaf(rr_, cm, ca);
    const float gr   = qperm<0x4E>(actr);
    const float or_  = qperm<0x1B>(actr);
    const float cr   = actr * gr;                      // sig(i)*tanh(g), c0 = 0
    const float e2r  = __builtin_amdgcn_exp2f(cr * (-2.0f * LOG2E));
    const float thr_ = fmaf(__builtin_amdgcn_rcpf(1.0f + e2r), 2.0f, -1.0f);
    const float hbw  = or_ * thr_;

    float hr[16];
#pragma unroll
    for (int n = 0; n < 16; ++n) hr[n] = rl(hbw, 4 * n);

    // ---- MLP head: hid = LeakyReLU([h_fwd, h_bwd] @ W1.T + b1); out = hid @ W2.T + b2
    const int m = lane & 15;
    float hid = b1[m];
#pragma unroll
    for (int n = 0; n < 16; ++n) hid = fmaf(hs[n], W1[m * 32 + n], hid);
#pragma unroll
    for (int n = 0; n < 16; ++n) hid = fmaf(hr[n], W1[m * 32 + 16 + n], hid);
    hid = (hid > 0.0f) ? hid : (0.2f * hid);

    float v = hid * W2[m];
    v += __shfl_xor(v, 1);
    v += __shfl_xor(v, 2);
    v += __shfl_xor(v, 4);
    v += __shfl_xor(v, 8);
    if (lane == 0) out[b] = v + b2[0];
}

extern "C" void kernel_launch(void* const* d_in, const int* in_sizes, int n_in,
                              void* d_out, int out_size, void* d_ws, size_t ws_size,
                              hipStream_t stream) {
    const float* x      = (const float*)d_in[0];
    const float* W_ih_f = (const float*)d_in[1];
    const float* W_hh_f = (const float*)d_in[2];
    const float* b_ih_f = (const float*)d_in[3];
    const float* b_hh_f = (const float*)d_in[4];
    const float* W_ih_r = (const float*)d_in[5];
    const float* W_hh_r = (const float*)d_in[6];
    const float* b_ih_r = (const float*)d_in[7];
    const float* b_hh_r = (const float*)d_in[8];
    const float* W1     = (const float*)d_in[9];
    const float* b1     = (const float*)d_in[10];
    const float* W2     = (const float*)d_in[11];
    const float* b2     = (const float*)d_in[12];
    float* out = (float*)d_out;

    const int B = in_sizes[0] / T_LEN;   // 2048
    dim3 grid(B / 4), block(256);
    size_t lds_bytes = 4 * 592 * sizeof(float);   // 9472 B/block
    hipLaunchKernelGGL(bilstm_head_kernel, grid, block, lds_bytes, stream,
                       x, W_ih_f, W_hh_f, b_ih_f, b_hh_f,
                       W_ih_r, W_hh_r, b_ih_r, b_hh_r,
                       W1, b1, W2, b2, out);
}

// Round 8
// 72.839 us; speedup vs baseline: 1.5670x; 1.1310x over previous
//
#include <hip/hip_runtime.h>

#define T_LEN 512
#define LOG2E 1.4426950408889634f

typedef float f32x2 __attribute__((ext_vector_type(2)));

// v7: 2 batches per wave. Lanes 0-31 = batch A, 32-63 = batch B.
// Within a half: hl=lane&31, k=hl>>1 (hidden idx), p=hl&1.
//   sub-row 0: row = p*16+k   (gate i if p=0, f if p=1; both sigmoid)
//   sub-row 1: row = (2+p)*16+k (gate g if p=0 [tanh], o if p=1 [sigmoid])
// Gates of hidden k live on lane pair (2k, 2k+1) -> one quad_perm[1,0,3,2]
// per sub-row gathers f and o. c/h computed on p=0 lanes.
// h broadcast: p0 lanes ds_write h[k]; whole half reads 4x ds_read_b128
// (uniform addr per half) -> pairs shared by both sub-rows' pk_fma matvec.
// LDS region per batch: [h 16][hbwd/dead 16][x 512][pad 16] = 560 floats.
__global__ __launch_bounds__(256, 1) void bilstm_head_kernel(
    const float* __restrict__ x,
    const float* __restrict__ W_ih_f, const float* __restrict__ W_hh_f,
    const float* __restrict__ b_ih_f, const float* __restrict__ b_hh_f,
    const float* __restrict__ W_ih_r, const float* __restrict__ W_hh_r,
    const float* __restrict__ b_ih_r, const float* __restrict__ b_hh_r,
    const float* __restrict__ W1, const float* __restrict__ b1,
    const float* __restrict__ W2, const float* __restrict__ b2,
    float* __restrict__ out)
{
    extern __shared__ float smem[];          // 4 waves * 2 * 560 floats

    const int tid  = threadIdx.x;
    const int wid  = tid >> 6;
    const int lane = tid & 63;
    const int half = lane >> 5;
    const int hl   = lane & 31;
    const int b    = blockIdx.x * 8 + wid * 2 + half;

    const int k = hl >> 1;
    const int p = hl & 1;
    const int row0 = p * 16 + k;             // sigmoid row (i or f)
    const int row1 = (2 + p) * 16 + k;       // g (tanh) or o (sigmoid)

    const float c1_0 = -LOG2E;
    const float c1_1 = (p == 0) ? (-2.0f * LOG2E) : (-LOG2E);
    const float cm1  = (p == 0) ? 2.0f : 1.0f;
    const float ca1  = (p == 0) ? -1.0f : 0.0f;
    const float k2   = -2.0f * LOG2E;

    // prescaled weights: matvec result feeds v_exp directly
    const float wih0  = W_ih_f[row0] * c1_0;
    const float bias0 = (b_ih_f[row0] + b_hh_f[row0]) * c1_0;
    const float wih1  = W_ih_f[row1] * c1_1;
    const float bias1 = (b_ih_f[row1] + b_hh_f[row1]) * c1_1;
    f32x2 w0p[8], w1p[8];
#pragma unroll
    for (int n = 0; n < 8; ++n) {
        w0p[n].x = W_hh_f[row0 * 16 + 2 * n]     * c1_0;
        w0p[n].y = W_hh_f[row0 * 16 + 2 * n + 1] * c1_0;
        w1p[n].x = W_hh_f[row1 * 16 + 2 * n]     * c1_1;
        w1p[n].y = W_hh_f[row1 * 16 + 2 * n + 1] * c1_1;
    }

    const int rbase = (wid * 2 + half) * 560;        // region base (floats)
    // stage this batch's x row (32 lanes per batch, 16 iters)
#pragma unroll
    for (int i = 0; i < 16; ++i)
        smem[rbase + 32 + i * 32 + hl] = x[b * T_LEN + i * 32 + hl];

    const unsigned vB = (unsigned)(rbase * 4);               // h-pair read base
    const unsigned vW = (unsigned)((rbase + p * 16 + k) * 4); // h write (p0->h[k])
    unsigned vX = (unsigned)(rbase * 4 + 96);                 // x base-32 (pre-bump)
    float c = 0.0f;

// One LSTM step (both batches, both sub-rows). DS outstanding at head:
// x(prefetched), write, r1..r4 -> staggered in-order waits.
#define LSTM_STEP(XC, XN, XOFF) \
    "s_waitcnt lgkmcnt(5)\n\t" \
    "v_fma_f32 v20, " XC ", %[wih0], %[bias0]\n\t" \
    "v_mov_b32 v21, 0\n\t" \
    "v_fma_f32 v22, " XC ", %[wih1], %[bias1]\n\t" \
    "v_mov_b32 v23, 0\n\t" \
    "s_waitcnt lgkmcnt(3)\n\t" \
    "v_pk_fma_f32 v[20:21], v[32:33], %[w00], v[20:21]\n\t" \
    "v_pk_fma_f32 v[22:23], v[32:33], %[w10], v[22:23]\n\t" \
    "v_pk_fma_f32 v[20:21], v[34:35], %[w01], v[20:21]\n\t" \
    "v_pk_fma_f32 v[22:23], v[34:35], %[w11], v[22:23]\n\t" \
    "s_waitcnt lgkmcnt(2)\n\t" \
    "v_pk_fma_f32 v[20:21], v[36:37], %[w02], v[20:21]\n\t" \
    "v_pk_fma_f32 v[22:23], v[36:37], %[w12], v[22:23]\n\t" \
    "v_pk_fma_f32 v[20:21], v[38:39], %[w03], v[20:21]\n\t" \
    "v_pk_fma_f32 v[22:23], v[38:39], %[w13], v[22:23]\n\t" \
    "s_waitcnt lgkmcnt(1)\n\t" \
    "v_pk_fma_f32 v[20:21], v[40:41], %[w04], v[20:21]\n\t" \
    "v_pk_fma_f32 v[22:23], v[40:41], %[w14], v[22:23]\n\t" \
    "v_pk_fma_f32 v[20:21], v[42:43], %[w05], v[20:21]\n\t" \
    "v_pk_fma_f32 v[22:23], v[42:43], %[w15], v[22:23]\n\t" \
    "s_waitcnt lgkmcnt(0)\n\t" \
    "v_pk_fma_f32 v[20:21], v[44:45], %[w06], v[20:21]\n\t" \
    "v_pk_fma_f32 v[22:23], v[44:45], %[w16], v[22:23]\n\t" \
    "v_pk_fma_f32 v[20:21], v[46:47], %[w07], v[20:21]\n\t" \
    "v_pk_fma_f32 v[22:23], v[46:47], %[w17], v[22:23]\n\t" \
    "v_add_f32 v20, v20, v21\n\t" \
    "v_add_f32 v22, v22, v23\n\t" \
    "v_exp_f32 v24, v20\n\t" \
    "v_exp_f32 v25, v22\n\t" \
    "ds_read_b32 " XN ", %[vX] offset:" XOFF "\n\t" \
    "v_add_f32 v24, 1.0, v24\n\t" \
    "v_add_f32 v25, 1.0, v25\n\t" \
    "v_rcp_f32 v24, v24\n\t" \
    "v_rcp_f32 v25, v25\n\t" \
    "s_nop 1\n\t" \
    "v_fma_f32 v25, v25, %[cm1], %[ca1]\n\t" \
    "s_nop 1\n\t" \
    "v_mov_b32_dpp v26, v24 quad_perm:[1,0,3,2] row_mask:0xf bank_mask:0xf\n\t" \
    "v_mov_b32_dpp v27, v25 quad_perm:[1,0,3,2] row_mask:0xf bank_mask:0xf\n\t" \
    "v_mul_f32 v28, v24, v25\n\t" \
    "v_fma_f32 %[c], v26, %[c], v28\n\t" \
    "v_mul_f32 v28, %[k2], %[c]\n\t" \
    "v_exp_f32 v28, v28\n\t" \
    "s_nop 1\n\t" \
    "v_add_f32 v28, 1.0, v28\n\t" \
    "v_rcp_f32 v28, v28\n\t" \
    "s_nop 1\n\t" \
    "v_fma_f32 v28, v28, 2.0, -1.0\n\t" \
    "v_mul_f32 v29, v27, v28\n\t" \
    "ds_write_b32 %[vW], v29\n\t" \
    "ds_read_b128 v[32:35], %[vB] offset:0\n\t" \
    "ds_read_b128 v[36:39], %[vB] offset:16\n\t" \
    "ds_read_b128 v[40:43], %[vB] offset:32\n\t" \
    "ds_read_b128 v[44:47], %[vB] offset:48\n\t"

    asm volatile(
        // preamble: mimic a step tail -> x0 read, zero-h write, 4 h reads
        "v_mov_b32 v29, 0\n\t"
        "ds_read_b32 v30, %[vB] offset:128\n\t"
        "ds_write_b32 %[vW], v29\n\t"
        "ds_read_b128 v[32:35], %[vB] offset:0\n\t"
        "ds_read_b128 v[36:39], %[vB] offset:16\n\t"
        "ds_read_b128 v[40:43], %[vB] offset:32\n\t"
        "ds_read_b128 v[44:47], %[vB] offset:48\n\t"
        "s_mov_b32 s20, 0\n\t"
        "1:\n\t"
        "v_add_u32 %[vX], 32, %[vX]\n\t"
        LSTM_STEP("v30", "v31", "4")
        LSTM_STEP("v31", "v30", "8")
        LSTM_STEP("v30", "v31", "12")
        LSTM_STEP("v31", "v30", "16")
        LSTM_STEP("v30", "v31", "20")
        LSTM_STEP("v31", "v30", "24")
        LSTM_STEP("v30", "v31", "28")
        LSTM_STEP("v31", "v30", "32")
        "s_add_u32 s20, s20, 1\n\t"
        "s_cmp_lt_u32 s20, 64\n\t"
        "s_cbranch_scc1 1b\n\t"
        "s_waitcnt lgkmcnt(0)\n\t"
        : [c]"+v"(c), [vX]"+v"(vX)
        : [vB]"v"(vB), [vW]"v"(vW),
          [wih0]"v"(wih0), [bias0]"v"(bias0),
          [wih1]"v"(wih1), [bias1]"v"(bias1),
          [cm1]"v"(cm1), [ca1]"v"(ca1), [k2]"v"(k2),
          [w00]"v"(w0p[0]), [w01]"v"(w0p[1]), [w02]"v"(w0p[2]), [w03]"v"(w0p[3]),
          [w04]"v"(w0p[4]), [w05]"v"(w0p[5]), [w06]"v"(w0p[6]), [w07]"v"(w0p[7]),
          [w10]"v"(w1p[0]), [w11]"v"(w1p[1]), [w12]"v"(w1p[2]), [w13]"v"(w1p[3]),
          [w14]"v"(w1p[4]), [w15]"v"(w1p[5]), [w16]"v"(w1p[6]), [w17]"v"(w1p[7])
        : "v20","v21","v22","v23","v24","v25","v26","v27","v28","v29",
          "v30","v31","v32","v33","v34","v35","v36","v37","v38","v39",
          "v40","v41","v42","v43","v44","v45","v46","v47",
          "s20","scc","memory");
#undef LSTM_STEP

    // ---- reverse direction: one LSTM step on x[:, T-1] from zero state ----
    // lanes hl<16 compute h_bwd[hl] for their batch (f-gate unused: c0=0)
    if (hl < 16) {
        const int j = hl;
        const float xl = smem[rbase + 32 + 511];
        const float zi = fmaf(xl, W_ih_r[j],      b_ih_r[j]      + b_hh_r[j]);
        const float zg = fmaf(xl, W_ih_r[32 + j], b_ih_r[32 + j] + b_hh_r[32 + j]);
        const float zo = fmaf(xl, W_ih_r[48 + j], b_ih_r[48 + j] + b_hh_r[48 + j]);
        const float si = __builtin_amdgcn_rcpf(1.0f + __builtin_amdgcn_exp2f(-zi * LOG2E));
        const float tg = fmaf(__builtin_amdgcn_rcpf(1.0f + __builtin_amdgcn_exp2f(-2.0f * zg * LOG2E)), 2.0f, -1.0f);
        const float so = __builtin_amdgcn_rcpf(1.0f + __builtin_amdgcn_exp2f(-zo * LOG2E));
        const float cr = si * tg;
        const float th = fmaf(__builtin_amdgcn_rcpf(1.0f + __builtin_amdgcn_exp2f(-2.0f * cr * LOG2E)), 2.0f, -1.0f);
        smem[rbase + 16 + j] = so * th;
    }
    __syncthreads();

    // ---- MLP head ----
    const int m = hl & 15;
    float hid = b1[m];
#pragma unroll
    for (int n = 0; n < 16; ++n) hid = fmaf(smem[rbase + n],      W1[m * 32 + n],      hid);
#pragma unroll
    for (int n = 0; n < 16; ++n) hid = fmaf(smem[rbase + 16 + n], W1[m * 32 + 16 + n], hid);
    hid = (hid > 0.0f) ? hid : (0.2f * hid);

    float v = hid * W2[m];
    v += __shfl_xor(v, 1);
    v += __shfl_xor(v, 2);
    v += __shfl_xor(v, 4);
    v += __shfl_xor(v, 8);
    if (hl == 0) out[b] = v + b2[0];
}

extern "C" void kernel_launch(void* const* d_in, const int* in_sizes, int n_in,
                              void* d_out, int out_size, void* d_ws, size_t ws_size,
                              hipStream_t stream) {
    const float* x      = (const float*)d_in[0];
    const float* W_ih_f = (const float*)d_in[1];
    const float* W_hh_f = (const float*)d_in[2];
    const float* b_ih_f = (const float*)d_in[3];
    const float* b_hh_f = (const float*)d_in[4];
    const float* W_ih_r = (const float*)d_in[5];
    const float* W_hh_r = (const float*)d_in[6];
    const float* b_ih_r = (const float*)d_in[7];
    const float* b_hh_r = (const float*)d_in[8];
    const float* W1     = (const float*)d_in[9];
    const float* b1     = (const float*)d_in[10];
    const float* W2     = (const float*)d_in[11];
    const float* b2     = (const float*)d_in[12];
    float* out = (float*)d_out;

    const int B = in_sizes[0] / T_LEN;   // 2048
    dim3 grid(B / 8), block(256);
    size_t lds_bytes = 8 * 560 * sizeof(float);   // 17920 B/block
    hipLaunchKernelGGL(bilstm_head_kernel, grid, block, lds_bytes, stream,
                       x, W_ih_f, W_hh_f, b_ih_f, b_hh_f,
                       W_ih_r, W_hh_r, b_ih_r, b_hh_r,
                       W1, b1, W2, b2, out);
}